// Round 1
// baseline (636.209 us; speedup 1.0000x reference)
//
#include <hip/hip_runtime.h>

// HashGridEncoding: N=2^20 points, 12 levels, T=2^19 entries/level, F=2 feats.
// out[n, l*2+f] = trilinear-weighted sum of 8 hashed corner features.

constexpr int NPTS     = 1 << 20;
constexpr int NLEVELS  = 12;
constexpr unsigned TMASK = (1u << 19) - 1u;   // T - 1
constexpr unsigned P1 = 2654435761u;
constexpr unsigned P2 = 805459861u;

__global__ __launch_bounds__(256, 4)
void hashgrid_kernel(const float* __restrict__ x,
                     const float* __restrict__ tables,
                     float* __restrict__ out)
{
    const int n = blockIdx.x * 256 + threadIdx.x;

    // x is (N,3) row-major: wave reads a contiguous 768B region -> L1-friendly.
    const float px = x[3 * n + 0];
    const float py = x[3 * n + 1];
    const float pz = x[3 * n + 2];

    // floor(16 * 1.38^l) for l=0..11 (verified in fp64)
    const float res[NLEVELS] = {16.f, 22.f, 30.f, 42.f, 58.f, 80.f,
                                110.f, 152.f, 210.f, 290.f, 400.f, 553.f};

    float o[2 * NLEVELS];

#pragma unroll
    for (int l = 0; l < NLEVELS; ++l) {
        const float r  = res[l];
        const float xs = px * r, ys = py * r, zs = pz * r;
        const float xf = floorf(xs), yf = floorf(ys), zf = floorf(zs);
        const float wx = xs - xf, wy = ys - yf, wz = zs - zf;
        const unsigned xi = (unsigned)xf, yi = (unsigned)yf, zi = (unsigned)zf;

        const float2* __restrict__ tab =
            reinterpret_cast<const float2*>(tables) + (size_t)l * (TMASK + 1u);

        // hash the 8 corners, issue all 8 gathers back-to-back
        unsigned idx[8];
#pragma unroll
        for (int c = 0; c < 8; ++c) {
            const unsigned ox = c & 1u, oy = (c >> 1) & 1u, oz = (c >> 2) & 1u;
            const unsigned h = (xi + ox) ^ ((yi + oy) * P1) ^ ((zi + oz) * P2);
            idx[c] = h & TMASK;
        }
        float2 f[8];
#pragma unroll
        for (int c = 0; c < 8; ++c) f[c] = tab[idx[c]];

        float f0 = 0.f, f1 = 0.f;
#pragma unroll
        for (int c = 0; c < 8; ++c) {
            const unsigned ox = c & 1u, oy = (c >> 1) & 1u, oz = (c >> 2) & 1u;
            const float w = (ox ? wx : 1.f - wx) *
                            (oy ? wy : 1.f - wy) *
                            (oz ? wz : 1.f - wz);
            f0 += w * f[c].x;
            f1 += w * f[c].y;
        }
        o[2 * l + 0] = f0;
        o[2 * l + 1] = f1;
    }

    // 24 floats per point, contiguous: 6 x float4 stores.
    float4* __restrict__ op = reinterpret_cast<float4*>(out + (size_t)n * 24);
#pragma unroll
    for (int i = 0; i < 6; ++i) {
        op[i] = make_float4(o[4 * i + 0], o[4 * i + 1], o[4 * i + 2], o[4 * i + 3]);
    }
}

extern "C" void kernel_launch(void* const* d_in, const int* in_sizes, int n_in,
                              void* d_out, int out_size, void* d_ws, size_t ws_size,
                              hipStream_t stream)
{
    const float* x      = reinterpret_cast<const float*>(d_in[0]);   // (N,3)
    const float* tables = reinterpret_cast<const float*>(d_in[1]);   // (12,T,2)
    float* out          = reinterpret_cast<float*>(d_out);           // (N,24)

    hashgrid_kernel<<<NPTS / 256, 256, 0, stream>>>(x, tables, out);
}

// Round 3
// 584.658 us; speedup vs baseline: 1.0882x; 1.0882x over previous
//
#include <hip/hip_runtime.h>

// HashGridEncoding: N=2^20 points, 12 levels, T=2^19 entries/level, F=2 feats.
// Level-major phase kernel (one level per blockIdx.y) so each XCD's 4MB L2
// holds the active level's 4MB table; then a transpose kernel -> (N,24).

constexpr int NPTS     = 1 << 20;
constexpr int NLEVELS  = 12;
constexpr unsigned T     = 1u << 19;
constexpr unsigned TMASK = T - 1u;
constexpr unsigned P1 = 2654435761u;
constexpr unsigned P2 = 805459861u;

// clang native vectors: legal operands for __builtin_nontemporal_*
typedef float vfloat2 __attribute__((ext_vector_type(2)));
typedef float vfloat4 __attribute__((ext_vector_type(4)));

// floor(16 * 1.38^l) for l=0..11 (verified in fp64)
__constant__ float c_res[NLEVELS] = {16.f, 22.f, 30.f, 42.f, 58.f, 80.f,
                                     110.f, 152.f, 210.f, 290.f, 400.f, 553.f};

__device__ __forceinline__ float2 encode_one_level(
    float px, float py, float pz, float r, const float2* __restrict__ tab)
{
    const float xs = px * r, ys = py * r, zs = pz * r;
    const float xf = floorf(xs), yf = floorf(ys), zf = floorf(zs);
    const float wx = xs - xf, wy = ys - yf, wz = zs - zf;
    const unsigned xi = (unsigned)xf, yi = (unsigned)yf, zi = (unsigned)zf;

    unsigned idx[8];
#pragma unroll
    for (int c = 0; c < 8; ++c) {
        const unsigned ox = c & 1u, oy = (c >> 1) & 1u, oz = (c >> 2) & 1u;
        const unsigned h = (xi + ox) ^ ((yi + oy) * P1) ^ ((zi + oz) * P2);
        idx[c] = h & TMASK;
    }
    float2 f[8];
#pragma unroll
    for (int c = 0; c < 8; ++c) f[c] = tab[idx[c]];

    float f0 = 0.f, f1 = 0.f;
#pragma unroll
    for (int c = 0; c < 8; ++c) {
        const unsigned ox = c & 1u, oy = (c >> 1) & 1u, oz = (c >> 2) & 1u;
        const float w = (ox ? wx : 1.f - wx) *
                        (oy ? wy : 1.f - wy) *
                        (oz ? wz : 1.f - wz);
        f0 += w * f[c].x;
        f1 += w * f[c].y;
    }
    return make_float2(f0, f1);
}

// Phase 1: grid (NPTS/256, NLEVELS). ws layout: (L, N) float2, coalesced
// non-temporal stores (don't evict the table from L2).
__global__ __launch_bounds__(256, 8)
void hashgrid_level_kernel(const float* __restrict__ x,
                           const float* __restrict__ tables,
                           float2* __restrict__ ws)
{
    const int n = blockIdx.x * 256 + threadIdx.x;
    const int l = blockIdx.y;

    const float px = x[3 * n + 0];
    const float py = x[3 * n + 1];
    const float pz = x[3 * n + 2];

    const float2* __restrict__ tab =
        reinterpret_cast<const float2*>(tables) + (size_t)l * T;

    const float2 f = encode_one_level(px, py, pz, c_res[l], tab);
    vfloat2 v = {f.x, f.y};
    __builtin_nontemporal_store(
        v, reinterpret_cast<vfloat2*>(&ws[(size_t)l * NPTS + n]));
}

// Phase 2: (L,N,2) -> (N, L*2). Reads coalesced per level, writes 6x float4.
__global__ __launch_bounds__(256, 8)
void hashgrid_transpose_kernel(const float2* __restrict__ ws,
                               float* __restrict__ out)
{
    const int n = blockIdx.x * 256 + threadIdx.x;
    float o[2 * NLEVELS];
#pragma unroll
    for (int l = 0; l < NLEVELS; ++l) {
        const vfloat2 f = __builtin_nontemporal_load(
            reinterpret_cast<const vfloat2*>(&ws[(size_t)l * NPTS + n]));
        o[2 * l + 0] = f.x;
        o[2 * l + 1] = f.y;
    }
    float* __restrict__ op = out + (size_t)n * 24;
#pragma unroll
    for (int i = 0; i < 6; ++i) {
        vfloat4 v = {o[4*i+0], o[4*i+1], o[4*i+2], o[4*i+3]};
        __builtin_nontemporal_store(
            v, reinterpret_cast<vfloat4*>(op + 4 * i));
    }
}

// Fallback (ws too small): round-1 point-major kernel, direct (N,24) writes.
__global__ __launch_bounds__(256, 4)
void hashgrid_fused_kernel(const float* __restrict__ x,
                           const float* __restrict__ tables,
                           float* __restrict__ out)
{
    const int n = blockIdx.x * 256 + threadIdx.x;
    const float px = x[3 * n + 0];
    const float py = x[3 * n + 1];
    const float pz = x[3 * n + 2];

    float o[2 * NLEVELS];
#pragma unroll
    for (int l = 0; l < NLEVELS; ++l) {
        const float2* __restrict__ tab =
            reinterpret_cast<const float2*>(tables) + (size_t)l * T;
        const float2 f = encode_one_level(px, py, pz, c_res[l], tab);
        o[2 * l + 0] = f.x;
        o[2 * l + 1] = f.y;
    }
    float4* __restrict__ op = reinterpret_cast<float4*>(out + (size_t)n * 24);
#pragma unroll
    for (int i = 0; i < 6; ++i)
        op[i] = make_float4(o[4*i+0], o[4*i+1], o[4*i+2], o[4*i+3]);
}

extern "C" void kernel_launch(void* const* d_in, const int* in_sizes, int n_in,
                              void* d_out, int out_size, void* d_ws, size_t ws_size,
                              hipStream_t stream)
{
    const float* x      = reinterpret_cast<const float*>(d_in[0]);   // (N,3)
    const float* tables = reinterpret_cast<const float*>(d_in[1]);   // (12,T,2)
    float* out          = reinterpret_cast<float*>(d_out);           // (N,24)

    const size_t ws_needed = (size_t)NLEVELS * NPTS * sizeof(float2); // ~100.7MB
    if (ws_size >= ws_needed) {
        float2* ws = reinterpret_cast<float2*>(d_ws);
        dim3 grid(NPTS / 256, NLEVELS);
        hashgrid_level_kernel<<<grid, 256, 0, stream>>>(x, tables, ws);
        hashgrid_transpose_kernel<<<NPTS / 256, 256, 0, stream>>>(ws, out);
    } else {
        hashgrid_fused_kernel<<<NPTS / 256, 256, 0, stream>>>(x, tables, out);
    }
}

// Round 4
// 409.999 us; speedup vs baseline: 1.5517x; 1.4260x over previous
//
#include <hip/hip_runtime.h>

// HashGridEncoding: N=2^20 points, 12 levels, T=2^19 entries/level, F=2 feats.
// Phase 1: level-major gather (one level per blockIdx.y) so each XCD's 4MB L2
// holds the active level's table. Phase 2: LDS-coalesced transpose -> (N,24).

constexpr int NPTS     = 1 << 20;
constexpr int NLEVELS  = 12;
constexpr unsigned T     = 1u << 19;
constexpr unsigned TMASK = T - 1u;
constexpr unsigned P1 = 2654435761u;
constexpr unsigned P2 = 805459861u;

// clang native vectors: legal operands for __builtin_nontemporal_*
typedef float vfloat2 __attribute__((ext_vector_type(2)));
typedef float vfloat4 __attribute__((ext_vector_type(4)));

// floor(16 * 1.38^l) for l=0..11 (verified in fp64)
__constant__ float c_res[NLEVELS] = {16.f, 22.f, 30.f, 42.f, 58.f, 80.f,
                                     110.f, 152.f, 210.f, 290.f, 400.f, 553.f};

__device__ __forceinline__ float2 encode_one_level(
    float px, float py, float pz, float r, const float2* __restrict__ tab)
{
    const float xs = px * r, ys = py * r, zs = pz * r;
    const float xf = floorf(xs), yf = floorf(ys), zf = floorf(zs);
    const float wx = xs - xf, wy = ys - yf, wz = zs - zf;
    const unsigned xi = (unsigned)xf, yi = (unsigned)yf, zi = (unsigned)zf;

    unsigned idx[8];
#pragma unroll
    for (int c = 0; c < 8; ++c) {
        const unsigned ox = c & 1u, oy = (c >> 1) & 1u, oz = (c >> 2) & 1u;
        const unsigned h = (xi + ox) ^ ((yi + oy) * P1) ^ ((zi + oz) * P2);
        idx[c] = h & TMASK;
    }
    float2 f[8];
#pragma unroll
    for (int c = 0; c < 8; ++c) f[c] = tab[idx[c]];

    float f0 = 0.f, f1 = 0.f;
#pragma unroll
    for (int c = 0; c < 8; ++c) {
        const unsigned ox = c & 1u, oy = (c >> 1) & 1u, oz = (c >> 2) & 1u;
        const float w = (ox ? wx : 1.f - wx) *
                        (oy ? wy : 1.f - wy) *
                        (oz ? wz : 1.f - wz);
        f0 += w * f[c].x;
        f1 += w * f[c].y;
    }
    return make_float2(f0, f1);
}

// Phase 1: grid (NPTS/256, NLEVELS). ws layout: (L, N) float2. NT stores are
// full-line (wave writes 512B contiguous) and keep the table resident in L2.
__global__ __launch_bounds__(256, 8)
void hashgrid_level_kernel(const float* __restrict__ x,
                           const float* __restrict__ tables,
                           float2* __restrict__ ws)
{
    const int n = blockIdx.x * 256 + threadIdx.x;
    const int l = blockIdx.y;

    const float px = x[3 * n + 0];
    const float py = x[3 * n + 1];
    const float pz = x[3 * n + 2];

    const float2* __restrict__ tab =
        reinterpret_cast<const float2*>(tables) + (size_t)l * T;

    const float2 f = encode_one_level(px, py, pz, c_res[l], tab);
    vfloat2 v = {f.x, f.y};
    __builtin_nontemporal_store(
        v, reinterpret_cast<vfloat2*>(&ws[(size_t)l * NPTS + n]));
}

// Phase 2: (L,N,2) -> (N, L*2) via LDS so global writes are lane-contiguous
// full-line float4s. Rows padded 24->25 words: bank (25t+2l)%32 is a full
// period-32 cycle over t -> conflict-free (2 lanes/bank).
__global__ __launch_bounds__(256, 8)
void hashgrid_transpose_kernel(const float2* __restrict__ ws,
                               float* __restrict__ out)
{
    __shared__ float lds[256 * 25];
    const int t = threadIdx.x;
    const int base = blockIdx.x * 256;

#pragma unroll
    for (int l = 0; l < NLEVELS; ++l) {
        const vfloat2 f = __builtin_nontemporal_load(
            reinterpret_cast<const vfloat2*>(&ws[(size_t)l * NPTS + base + t]));
        lds[t * 25 + 2 * l + 0] = f.x;
        lds[t * 25 + 2 * l + 1] = f.y;
    }
    __syncthreads();

    // Block's output region: 256*24 floats = 1536 float4, lane-contiguous.
    float* __restrict__ ob = out + (size_t)base * 24;
#pragma unroll
    for (int i = 0; i < 6; ++i) {
        const int j  = i * 256 + t;   // float4 index within block
        const int f0 = 4 * j;         // flat float offset
        const int p  = f0 / 24;       // local point
        const int c  = f0 % 24;       // component (multiple of 4)
        vfloat4 v = {lds[p * 25 + c + 0], lds[p * 25 + c + 1],
                     lds[p * 25 + c + 2], lds[p * 25 + c + 3]};
        __builtin_nontemporal_store(v, reinterpret_cast<vfloat4*>(ob + f0));
    }
}

// Fallback (ws too small): point-major fused kernel, direct (N,24) writes.
__global__ __launch_bounds__(256, 4)
void hashgrid_fused_kernel(const float* __restrict__ x,
                           const float* __restrict__ tables,
                           float* __restrict__ out)
{
    const int n = blockIdx.x * 256 + threadIdx.x;
    const float px = x[3 * n + 0];
    const float py = x[3 * n + 1];
    const float pz = x[3 * n + 2];

    float o[2 * NLEVELS];
#pragma unroll
    for (int l = 0; l < NLEVELS; ++l) {
        const float2* __restrict__ tab =
            reinterpret_cast<const float2*>(tables) + (size_t)l * T;
        const float2 f = encode_one_level(px, py, pz, c_res[l], tab);
        o[2 * l + 0] = f.x;
        o[2 * l + 1] = f.y;
    }
    float4* __restrict__ op = reinterpret_cast<float4*>(out + (size_t)n * 24);
#pragma unroll
    for (int i = 0; i < 6; ++i)
        op[i] = make_float4(o[4*i+0], o[4*i+1], o[4*i+2], o[4*i+3]);
}

extern "C" void kernel_launch(void* const* d_in, const int* in_sizes, int n_in,
                              void* d_out, int out_size, void* d_ws, size_t ws_size,
                              hipStream_t stream)
{
    const float* x      = reinterpret_cast<const float*>(d_in[0]);   // (N,3)
    const float* tables = reinterpret_cast<const float*>(d_in[1]);   // (12,T,2)
    float* out          = reinterpret_cast<float*>(d_out);           // (N,24)

    const size_t ws_needed = (size_t)NLEVELS * NPTS * sizeof(float2); // ~100.7MB
    if (ws_size >= ws_needed) {
        float2* ws = reinterpret_cast<float2*>(d_ws);
        dim3 grid(NPTS / 256, NLEVELS);
        hashgrid_level_kernel<<<grid, 256, 0, stream>>>(x, tables, ws);
        hashgrid_transpose_kernel<<<NPTS / 256, 256, 0, stream>>>(ws, out);
    } else {
        hashgrid_fused_kernel<<<NPTS / 256, 256, 0, stream>>>(x, tables, out);
    }
}